// Round 8
// baseline (1601.004 us; speedup 1.0000x reference)
//
#include <hip/hip_runtime.h>
#include <math.h>

namespace {
constexpr int BB = 32, NPG = 4096, NTOT = BB*NPG, C = 128, FIN = 64, KK = 32, JJ = 40;
constexpr int YROWS = BB*JJ; // 1280
constexpr float EPS = 1e-5f;

// workspace layout (float offsets). All fp32.
constexpr size_t X_OFF   = 0;                                  // NTOT*128
constexpr size_t I_OFF   = (size_t)NTOT*C;                     // NTOT*40
constexpr size_t TY_OFF  = I_OFF + (size_t)NTOT*JJ;            // 1280*128
constexpr size_t YP_OFF  = TY_OFF + (size_t)YROWS*C;           // 1280*32
constexpr size_t PM_OFF  = YP_OFF + (size_t)YROWS*KK;          // 32*40*32
constexpr size_t PS_OFF  = PM_OFF + 40960;                     // 32*40*32
constexpr size_t ST_OFF  = PS_OFF + 40960;                     // 4 doubles (even offset)
}

// ---------------------------------------------------------------------------
// K1: out[r][c] = in[r][0:64] . W[c][0:64] + b[c]; accumulate sum/sumsq (double).
// ---------------------------------------------------------------------------
__global__ __launch_bounds__(256,3)
void k_gemm_in(const float* __restrict__ inp, const float* __restrict__ W,
               const float* __restrict__ bias, float* __restrict__ outp,
               double* __restrict__ stats) {
  __shared__ float in_t[64*64];          // 16384 B
  __shared__ float w_l[128*64];          // 32768 B
  __shared__ double dred[8];
  const int t = threadIdx.x;
  const int r0 = blockIdx.x * 64;
  #pragma unroll
  for (int s = 0; s < 4; ++s) {
    int f = (t + 256*s) * 4;
    int r = f >> 6, d = f & 63;
    float4 v = *(const float4*)(inp + (size_t)r0*FIN + f);
    *(float4*)(in_t + r*64 + (d ^ ((r & 7) * 8))) = v;
  }
  #pragma unroll
  for (int s = 0; s < 8; ++s) {
    int f = (t + 256*s) * 4;
    int r = f >> 6, d = f & 63;
    float4 w = *(const float4*)(W + f);
    *(float4*)(w_l + r*64 + (d ^ ((r & 7) * 8))) = w;
  }
  __syncthreads();
  const int rg = t >> 4;                 // rows r = rg + 16*i, i<4
  const int cg = t & 15;                 // cols c = cg + 16*j, j<8
  const int swi = (rg & 7) * 8;
  const int sww = (cg & 7) * 8;
  float acc[4][8];
  #pragma unroll
  for (int i=0;i<4;i++)
    #pragma unroll
    for (int j=0;j<8;j++) acc[i][j] = 0.f;
  #pragma unroll
  for (int dc = 0; dc < 16; ++dc) {
    const int d = dc*4;
    const int di = d ^ swi, dw = d ^ sww;
    float4 a[4], w4[8];
    #pragma unroll
    for (int i=0;i<4;i++) a[i]  = *(const float4*)(in_t + (rg+16*i)*64 + di);
    #pragma unroll
    for (int j=0;j<8;j++) w4[j] = *(const float4*)(w_l  + (cg+16*j)*64 + dw);
    #pragma unroll
    for (int i=0;i<4;i++)
      #pragma unroll
      for (int j=0;j<8;j++)
        acc[i][j] += a[i].x*w4[j].x + a[i].y*w4[j].y + a[i].z*w4[j].z + a[i].w*w4[j].w;
  }
  double ds = 0.0, dss = 0.0;
  #pragma unroll
  for (int i=0;i<4;i++) {
    const size_t r = (size_t)r0 + rg + 16*i;
    #pragma unroll
    for (int j=0;j<8;j++) {
      const int c = cg + 16*j;
      float v = acc[i][j] + bias[c];
      outp[r*C + c] = v;
      ds += (double)v; dss += (double)v*(double)v;
    }
  }
  #pragma unroll
  for (int off = 32; off > 0; off >>= 1) {
    ds  += __shfl_down(ds, off);
    dss += __shfl_down(dss, off);
  }
  if ((t & 63) == 0) { dred[(t>>6)*2] = ds; dred[(t>>6)*2+1] = dss; }
  __syncthreads();
  if (t == 0) {
    atomicAdd(stats+0, dred[0]+dred[2]+dred[4]+dred[6]);
    atomicAdd(stats+1, dred[1]+dred[3]+dred[5]+dred[7]);
  }
}

// ---------------------------------------------------------------------------
// K3: y_p[row][k] = relu(q[k]*relu( ((ty-my)*ry) . V[:,k] )); 32 rows/block.
// ---------------------------------------------------------------------------
__global__ __launch_bounds__(256)
void k_yp(const float* __restrict__ ty, const float* __restrict__ V,
          const float* __restrict__ q, const double* __restrict__ ST,
          float* __restrict__ yp) {
  __shared__ float ty_l[32*132];
  __shared__ float vt_l[32*132];
  __shared__ float q_l[32];
  const int t = threadIdx.x;
  const int r0 = blockIdx.x * 32;
  double cy = (double)YROWS * (double)C;
  double myd = ST[2]/cy, vy = ST[3]/cy - myd*myd;
  const float my = (float)myd;
  const float ry = (float)(1.0/sqrt(vy + (double)EPS));
  #pragma unroll
  for (int s=0;s<4;s++) {
    int f = (t + 256*s)*4;
    int r = f >> 7, d = f & 127;
    float4 v = *(const float4*)(ty + (size_t)(r0+r)*C + d);
    v.x = (v.x-my)*ry; v.y = (v.y-my)*ry; v.z = (v.z-my)*ry; v.w = (v.w-my)*ry;
    *(float4*)(ty_l + r*132 + d) = v;
  }
  #pragma unroll
  for (int s=0;s<4;s++) {                 // V[d][k] -> vt[k][d]
    int f = (t + 256*s)*4;
    int d = f >> 5, k = f & 31;
    float4 v = *(const float4*)(V + f);
    vt_l[(k+0)*132 + d] = v.x;
    vt_l[(k+1)*132 + d] = v.y;
    vt_l[(k+2)*132 + d] = v.z;
    vt_l[(k+3)*132 + d] = v.w;
  }
  if (t < 32) q_l[t] = q[t];
  __syncthreads();
  const int rg = t >> 3;                  // one row
  const int kg = t & 7;                   // k = kg + 8*j
  float acc[4] = {0.f,0.f,0.f,0.f};
  #pragma unroll
  for (int dc=0; dc<32; ++dc) {
    const int d = dc*4;
    float4 a = *(const float4*)(ty_l + rg*132 + d);
    #pragma unroll
    for (int j=0;j<4;j++) {
      float4 w = *(const float4*)(vt_l + (kg+8*j)*132 + d);
      acc[j] += a.x*w.x + a.y*w.y + a.z*w.z + a.w*w.w;
    }
  }
  #pragma unroll
  for (int j=0;j<4;j++) {
    const int k = kg + 8*j;
    float v = fmaxf(acc[j], 0.f);
    v = fmaxf(q_l[k]*v, 0.f);
    yp[(size_t)(r0+rg)*KK + k] = v;
  }
}

// ---------------------------------------------------------------------------
// K4 register-resident with (a) register double-buffer prefetch of X/U chunks,
// (b) coalesced I write (all 4 kq lanes write disjoint float4s of their row).
// 128 rows/block; thread owns rows {r2, r2+64}, k-slice {kq+4i}. 29.5 KB LDS.
// MODE 0: write I fp32 + per-block (max, sumexp). MODE 1: out = sigm(sum I^2).
// ---------------------------------------------------------------------------
template<int MODE>
__global__ __launch_bounds__(256,4)
void k_xpI(const float* __restrict__ X, const float* __restrict__ U,
           const float* __restrict__ yp, const double* __restrict__ ST,
           float* __restrict__ Ibf, float* __restrict__ Pm,
           float* __restrict__ Ps, float* __restrict__ outp, const int normFlag) {
  __shared__ float xst[128*36];           // 18432 B
  __shared__ float utc[32*36];            // 4608 B  (U chunk, [k][d_local])
  __shared__ float ypt[32*44];            // 5632 B  ([k][j] padded)
  __shared__ float sredm[4*40];
  __shared__ float sreds[4*40];
  __shared__ float redm[40];
  const int t = threadIdx.x;
  const int bid = blockIdx.x;
  const int b = bid >> 5, blk = bid & 31;
  const size_t rowbase = (size_t)b*NPG + (size_t)blk*128;
  float sc = 1.f, sh = 0.f;
  if (normFlag) {
    double cx = (double)NTOT * (double)C;
    double mx = ST[0]/cx, vx = ST[1]/cx - mx*mx;
    float mxf = (float)mx, rx = (float)(1.0/sqrt(vx + (double)EPS));
    sc = rx; sh = -mxf*rx;
  }
  for (int f = t; f < 1280; f += 256) {   // yp[b][j][k] -> ypt[k][j]
    int j = f >> 5, k = f & 31;
    ypt[k*44 + j] = yp[(size_t)b*(JJ*KK) + f];
  }
  const int r2 = t >> 2;                  // rows r2, r2+64
  const int kq = t & 3;                   // k = kq + 4*i, i<8

  // prefetch chunk 0 into registers
  float4 xpre[4];
  float  upre[4];
  #pragma unroll
  for (int s=0;s<4;s++) {
    int idx = t + 256*s;
    int row = idx >> 3, q4 = (idx & 7)*4;
    xpre[s] = *(const float4*)(X + (rowbase+row)*C + q4);
  }
  #pragma unroll
  for (int s=0;s<4;s++) {
    int idx = t + 256*s;
    int dl = idx >> 5, k = idx & 31;
    upre[s] = U[(size_t)dl*KK + k];
  }

  float acc[2][8];
  #pragma unroll
  for (int pi=0; pi<2; ++pi)
    #pragma unroll
    for (int i=0;i<8;i++) acc[pi][i] = 0.f;

  for (int cc=0; cc<4; ++cc) {
    // write prefetched chunk to LDS (X normalized)
    #pragma unroll
    for (int s=0;s<4;s++) {
      int idx = t + 256*s;
      int row = idx >> 3, q4 = (idx & 7)*4;
      float4 v = xpre[s];
      v.x = v.x*sc + sh; v.y = v.y*sc + sh;
      v.z = v.z*sc + sh; v.w = v.w*sc + sh;
      *(float4*)(xst + row*36 + q4) = v;
    }
    #pragma unroll
    for (int s=0;s<4;s++) {
      int idx = t + 256*s;
      int dl = idx >> 5, k = idx & 31;
      utc[k*36 + dl] = upre[s];
    }
    __syncthreads();
    if (cc < 3) {                         // issue next chunk's loads (overlap compute)
      const int d0n = (cc+1)*32;
      #pragma unroll
      for (int s=0;s<4;s++) {
        int idx = t + 256*s;
        int row = idx >> 3, q4 = (idx & 7)*4;
        xpre[s] = *(const float4*)(X + (rowbase+row)*C + d0n + q4);
      }
      #pragma unroll
      for (int s=0;s<4;s++) {
        int idx = t + 256*s;
        int dl = idx >> 5, k = idx & 31;
        upre[s] = U[(size_t)(d0n+dl)*KK + k];
      }
    }
    #pragma unroll
    for (int dd4=0; dd4<8; ++dd4) {
      const int dd = dd4*4;
      float4 a0 = *(const float4*)(xst + r2*36 + dd);
      float4 a1 = *(const float4*)(xst + (r2+64)*36 + dd);
      #pragma unroll
      for (int i=0;i<8;i++) {
        float4 w = *(const float4*)(utc + (kq+4*i)*36 + dd);
        acc[0][i] += a0.x*w.x + a0.y*w.y + a0.z*w.z + a0.w*w.w;
        acc[1][i] += a1.x*w.x + a1.y*w.y + a1.z*w.z + a1.w*w.w;
      }
    }
    __syncthreads();
  }
  float xp[2][8];
  #pragma unroll
  for (int pi=0; pi<2; ++pi)
    #pragma unroll
    for (int i=0;i<8;i++) xp[pi][i] = fmaxf(acc[pi][i], 0.f);

  float ev[2][10];                        // I[row][4m+kq] extracts (MODE 0)
  float oa[2];                            // sum_j I^2 (MODE 1)
  #pragma unroll
  for (int pi=0; pi<2; ++pi) {
    float4 p[10];
    #pragma unroll
    for (int m=0;m<10;m++) { p[m].x=0.f; p[m].y=0.f; p[m].z=0.f; p[m].w=0.f; }
    #pragma unroll
    for (int i=0;i<8;i++) {
      const float xv = xp[pi][i];
      const float* yb = ypt + (kq+4*i)*44;
      #pragma unroll
      for (int m=0;m<10;m++) {
        float4 yv = *(const float4*)(yb + 4*m);
        p[m].x += xv*yv.x; p[m].y += xv*yv.y;
        p[m].z += xv*yv.z; p[m].w += xv*yv.w;
      }
    }
    #pragma unroll
    for (int m=0;m<10;m++) {              // cross-kq reduce -> full I on all 4 lanes
      p[m].x += __shfl_xor(p[m].x,1); p[m].x += __shfl_xor(p[m].x,2);
      p[m].y += __shfl_xor(p[m].y,1); p[m].y += __shfl_xor(p[m].y,2);
      p[m].z += __shfl_xor(p[m].z,1); p[m].z += __shfl_xor(p[m].z,2);
      p[m].w += __shfl_xor(p[m].w,1); p[m].w += __shfl_xor(p[m].w,2);
    }
    if (MODE == 0) {
      // coalesced I write: lane kq writes m = kq, kq+4, kq+8 (<10).
      // A wave's 64 lanes cover a contiguous 2560-B span of Ibf.
      float* dst = Ibf + (rowbase + r2 + 64*pi)*JJ;
      #pragma unroll
      for (int u=0;u<3;u++) {
        int m = kq + 4*u;
        if (m < 10) *(float4*)(dst + 4*m) = p[m];
      }
      #pragma unroll
      for (int m=0;m<10;m++) {            // extract j = 4m+kq component
        float4 qv = p[m];
        ev[pi][m] = (kq&1) ? ((kq&2)? qv.w : qv.y) : ((kq&2)? qv.z : qv.x);
      }
    } else {
      float s = 0.f;
      #pragma unroll
      for (int m=0;m<10;m++)
        s += p[m].x*p[m].x + p[m].y*p[m].y + p[m].z*p[m].z + p[m].w*p[m].w;
      oa[pi] = s;
    }
  }
  if (MODE == 0) {
    const int w = t >> 6, tl = t & 63;
    float mv[10];
    #pragma unroll
    for (int m=0;m<10;m++) {              // max over both rows + wave's 16 r2
      mv[m] = fmaxf(ev[0][m], ev[1][m]);
      mv[m] = fmaxf(mv[m], __shfl_xor(mv[m], 4));
      mv[m] = fmaxf(mv[m], __shfl_xor(mv[m], 8));
      mv[m] = fmaxf(mv[m], __shfl_xor(mv[m], 16));
      mv[m] = fmaxf(mv[m], __shfl_xor(mv[m], 32));
    }
    if (tl < 4) {
      #pragma unroll
      for (int m=0;m<10;m++) sredm[w*40 + 4*m + kq] = mv[m];
    }
    __syncthreads();
    if (t < 40)
      redm[t] = fmaxf(fmaxf(sredm[t], sredm[40+t]), fmaxf(sredm[80+t], sredm[120+t]));
    __syncthreads();
    float es[10];
    #pragma unroll
    for (int m=0;m<10;m++) {
      float M = redm[4*m + kq];
      es[m] = __expf(ev[0][m]-M) + __expf(ev[1][m]-M);
      es[m] += __shfl_xor(es[m], 4);
      es[m] += __shfl_xor(es[m], 8);
      es[m] += __shfl_xor(es[m], 16);
      es[m] += __shfl_xor(es[m], 32);
    }
    if (tl < 4) {
      #pragma unroll
      for (int m=0;m<10;m++) sreds[w*40 + 4*m + kq] = es[m];
    }
    __syncthreads();
    if (t < 40) {
      size_t po = ((size_t)b*40 + t)*32 + blk;
      Pm[po] = redm[t];
      Ps[po] = sreds[t]+sreds[40+t]+sreds[80+t]+sreds[120+t];
    }
  } else {
    if (kq == 0) {
      outp[rowbase + r2]      = 1.f/(1.f+__expf(-oa[0]));
      outp[rowbase + r2 + 64] = 1.f/(1.f+__expf(-oa[1]));
    }
  }
}

// ---------------------------------------------------------------------------
// K6: e = exp(I-M)/S; h = relu(e@yp); h2 = h@V^T; z = sigm([x,h2].gW + gb);
//     x = (1-z)x + z*h2. (M,S) combined inline from PM/PS; nrm inline from ST.
// ---------------------------------------------------------------------------
__global__ __launch_bounds__(256,4)
void k_update(float* __restrict__ x, const float* __restrict__ Ibf,
              const float* __restrict__ yp, const float* __restrict__ V,
              const float* __restrict__ gw, const float* __restrict__ gb,
              const float* __restrict__ Pm, const float* __restrict__ Ps,
              const double* __restrict__ ST, const int normFlag) {
  __shared__ float uni[128*36];           // e (64x40) phases A/B, then V (128x36)
  __shared__ float h_l[64*36];
  __shared__ float ypt[32*40];
  __shared__ float M_l[40], Si_l[40];
  __shared__ float gx_l[128], gh_l[128];
  const int t = threadIdx.x;
  const int bid = blockIdx.x;
  const int b   = bid >> 6;               // 64 blocks per graph
  const int blk = bid & 63;
  const size_t rowbase = (size_t)b*NPG + (size_t)blk*64;
  float sc = 1.f, sh = 0.f;
  if (normFlag) {
    double cx = (double)NTOT * (double)C;
    double mx = ST[0]/cx, vx = ST[1]/cx - mx*mx;
    float mxf = (float)mx, rx = (float)(1.0/sqrt(vx + (double)EPS));
    sc = rx; sh = -mxf*rx;
  }
  if (t < 40) {                           // inline k_comb
    const float* pm = Pm + ((size_t)b*40 + t)*32;
    const float* ps = Ps + ((size_t)b*40 + t)*32;
    float M = 0.f;
    #pragma unroll
    for (int k=0;k<32;k++) M = fmaxf(M, pm[k]);
    float S = 0.f;
    #pragma unroll
    for (int k=0;k<32;k++) S += ps[k]*__expf(pm[k]-M);
    M_l[t] = M; Si_l[t] = 1.f/S;
  }
  if (t < 128) gx_l[t] = gw[t];
  else gh_l[t-128] = gw[t];
  for (int f4 = t; f4 < 320; f4 += 256) { // yp[b] -> ypt[k][j]
    int f = f4*4;
    int j = f >> 5;
    float4 v = *(const float4*)(yp + (size_t)b*(JJ*KK) + f);
    int k = f & 31;
    ypt[(k+0)*40 + j] = v.x;
    ypt[(k+1)*40 + j] = v.y;
    ypt[(k+2)*40 + j] = v.z;
    ypt[(k+3)*40 + j] = v.w;
  }
  __syncthreads();
  for (int f4 = t; f4 < 640; f4 += 256) { // e staging (64x40) from fp32 I
    int f = f4*4;
    int n = f / 40, j = f - n*40;
    float4 v = *(const float4*)(Ibf + (rowbase + n)*JJ + j);
    float4 e;
    e.x = __expf(v.x - M_l[j+0]) * Si_l[j+0];
    e.y = __expf(v.y - M_l[j+1]) * Si_l[j+1];
    e.z = __expf(v.z - M_l[j+2]) * Si_l[j+2];
    e.w = __expf(v.w - M_l[j+3]) * Si_l[j+3];
    *(float4*)(uni + n*40 + j) = e;
  }
  __syncthreads();
  { // phase B: h[n][k] = relu(sum_j e*yp)
    const int rg = t >> 3;                // r = rg + 32*i, i<2
    const int kg = t & 7;                 // k = kg + 8*j2, j2<4
    float hacc[2][4];
    #pragma unroll
    for (int i=0;i<2;i++)
      #pragma unroll
      for (int j2=0;j2<4;j2++) hacc[i][j2] = 0.f;
    #pragma unroll
    for (int jc=0;jc<10;jc++) {
      const int jj = jc*4;
      float4 yv[4];
      #pragma unroll
      for (int j2=0;j2<4;j2++) yv[j2] = *(const float4*)(ypt + (kg+8*j2)*40 + jj);
      #pragma unroll
      for (int i=0;i<2;i++) {
        float4 ev = *(const float4*)(uni + (rg+32*i)*40 + jj);
        #pragma unroll
        for (int j2=0;j2<4;j2++)
          hacc[i][j2] += ev.x*yv[j2].x + ev.y*yv[j2].y + ev.z*yv[j2].z + ev.w*yv[j2].w;
      }
    }
    #pragma unroll
    for (int i=0;i<2;i++)
      #pragma unroll
      for (int j2=0;j2<4;j2++)
        h_l[(rg+32*i)*36 + kg + 8*j2] = fmaxf(hacc[i][j2], 0.f);
  }
  __syncthreads();
  #pragma unroll
  for (int s=0;s<4;s++) {                 // stage V into uni (e dead)
    int f = (t + 256*s)*4;
    *(float4*)(uni + (f>>5)*36 + (f&31)) = *(const float4*)(V + f);
  }
  __syncthreads();
  // phase C: h2 = h@V^T
  const int rg3 = t >> 4;                 // rows rg3*4 + i, i<4
  const int cg  = t & 15;                 // cols cg + 16*j3, j3<8
  float h2[4][8];
  #pragma unroll
  for (int i=0;i<4;i++)
    #pragma unroll
    for (int j3=0;j3<8;j3++) h2[i][j3] = 0.f;
  #pragma unroll
  for (int kc=0;kc<8;kc++) {
    const int kk2 = kc*4;
    float4 vv[8];
    #pragma unroll
    for (int j3=0;j3<8;j3++) vv[j3] = *(const float4*)(uni + (cg+16*j3)*36 + kk2);
    #pragma unroll
    for (int i=0;i<4;i++) {
      float4 hv = *(const float4*)(h_l + (rg3*4+i)*36 + kk2);
      #pragma unroll
      for (int j3=0;j3<8;j3++)
        h2[i][j3] += hv.x*vv[j3].x + hv.y*vv[j3].y + hv.z*vv[j3].z + hv.w*vv[j3].w;
    }
  }
  float xn[4][8];
  float gpv[4];
  #pragma unroll
  for (int i=0;i<4;i++) {
    float g = 0.f;
    const size_t rr = (rowbase + rg3*4 + i)*C;
    #pragma unroll
    for (int j3=0;j3<8;j3++) {
      const int c = cg + 16*j3;
      float xv = x[rr + c]*sc + sh;
      xn[i][j3] = xv;
      g += gx_l[c]*xv + gh_l[c]*h2[i][j3];
    }
    gpv[i] = g;
  }
  #pragma unroll
  for (int i=0;i<4;i++) {                 // reduce over the 16 cg lanes
    gpv[i] += __shfl_xor(gpv[i], 1);
    gpv[i] += __shfl_xor(gpv[i], 2);
    gpv[i] += __shfl_xor(gpv[i], 4);
    gpv[i] += __shfl_xor(gpv[i], 8);
  }
  const float gbv = gb[0];
  #pragma unroll
  for (int i=0;i<4;i++) {
    const float z = 1.f/(1.f + __expf(-(gpv[i] + gbv)));
    const size_t rr = (rowbase + rg3*4 + i)*C;
    #pragma unroll
    for (int j3=0;j3<8;j3++) {
      const int c = cg + 16*j3;
      x[rr + c] = (1.f - z)*xn[i][j3] + z*h2[i][j3];
    }
  }
}

extern "C" void kernel_launch(void* const* d_in, const int* in_sizes, int n_in,
                              void* d_out, int out_size, void* d_ws, size_t ws_size,
                              hipStream_t stream) {
  const float* nf  = (const float*)d_in[0];
  const float* fe  = (const float*)d_in[1];
  const float* W   = (const float*)d_in[2];
  const float* bin = (const float*)d_in[3];
  const float* U   = (const float*)d_in[4];
  const float* V   = (const float*)d_in[5];
  const float* q   = (const float*)d_in[6];
  const float* gw  = (const float*)d_in[7];
  const float* gb  = (const float*)d_in[8];
  float* out = (float*)d_out;
  float* wf  = (float*)d_ws;

  float*  X   = wf + X_OFF;
  float*  Ibf = wf + I_OFF;
  float*  TY  = wf + TY_OFF;
  float*  YP  = wf + YP_OFF;
  float*  PM  = wf + PM_OFF;
  float*  PS  = wf + PS_OFF;
  double* ST  = (double*)(wf + ST_OFF);

  hipMemsetAsync(ST, 0, 4*sizeof(double), stream);

  k_gemm_in<<<NTOT/64, 256, 0, stream>>>(nf, W, bin, X, ST);
  k_gemm_in<<<YROWS/64, 256, 0, stream>>>(fe, W, bin, TY, ST+2);
  k_yp<<<YROWS/32, 256, 0, stream>>>(TY, V, q, ST, YP);

  // layer 0
  k_xpI<0><<<1024, 256, 0, stream>>>(X, U, YP, ST, Ibf, PM, PS, nullptr, 1);
  k_update<<<2048, 256, 0, stream>>>(X, Ibf, YP, V, gw, gb, PM, PS, ST, 1);
  // layer 1
  k_xpI<0><<<1024, 256, 0, stream>>>(X, U, YP, ST, Ibf, PM, PS, nullptr, 0);
  k_update<<<2048, 256, 0, stream>>>(X, Ibf, YP, V, gw, gb, PM, PS, ST, 0);
  // layer 2 (final): out = sigmoid(sum_j I^2)
  k_xpI<1><<<1024, 256, 0, stream>>>(X, U, YP, ST, nullptr, nullptr, nullptr, out, 0);
}

// Round 9
// 379.961 us; speedup vs baseline: 4.2136x; 4.2136x over previous
//
#include <hip/hip_runtime.h>
#include <math.h>

namespace {
constexpr int BB = 32, NPG = 4096, NTOT = BB*NPG, C = 128, FIN = 64, KK = 32, JJ = 40;
constexpr int YROWS = BB*JJ; // 1280
constexpr float EPS = 1e-5f;

// workspace layout (float offsets). All fp32.
constexpr size_t X_OFF   = 0;                                  // NTOT*128
constexpr size_t I_OFF   = (size_t)NTOT*C;                     // NTOT*40
constexpr size_t TY_OFF  = I_OFF + (size_t)NTOT*JJ;            // 1280*128
constexpr size_t YP_OFF  = TY_OFF + (size_t)YROWS*C;           // 1280*32
constexpr size_t PM_OFF  = YP_OFF + (size_t)YROWS*KK;          // 32*40*32   (layer0)
constexpr size_t PS_OFF  = PM_OFF + 40960;                     // 32*40*32
constexpr size_t PM2_OFF = PS_OFF + 40960;                     // 32*40*64   (fused out)
constexpr size_t PS2_OFF = PM2_OFF + 81920;                    // 32*40*64
constexpr size_t ST_OFF  = PS2_OFF + 81920;                    // 4 doubles (even offset)
}

// ---------------------------------------------------------------------------
// K1: out[r][c] = in[r][0:64] . W[c][0:64] + b[c]; accumulate sum/sumsq (double).
// ---------------------------------------------------------------------------
__global__ __launch_bounds__(256,3)
void k_gemm_in(const float* __restrict__ inp, const float* __restrict__ W,
               const float* __restrict__ bias, float* __restrict__ outp,
               double* __restrict__ stats) {
  __shared__ float in_t[64*64];          // 16384 B
  __shared__ float w_l[128*64];          // 32768 B
  __shared__ double dred[8];
  const int t = threadIdx.x;
  const int r0 = blockIdx.x * 64;
  #pragma unroll
  for (int s = 0; s < 4; ++s) {
    int f = (t + 256*s) * 4;
    int r = f >> 6, d = f & 63;
    float4 v = *(const float4*)(inp + (size_t)r0*FIN + f);
    *(float4*)(in_t + r*64 + (d ^ ((r & 7) * 8))) = v;
  }
  #pragma unroll
  for (int s = 0; s < 8; ++s) {
    int f = (t + 256*s) * 4;
    int r = f >> 6, d = f & 63;
    float4 w = *(const float4*)(W + f);
    *(float4*)(w_l + r*64 + (d ^ ((r & 7) * 8))) = w;
  }
  __syncthreads();
  const int rg = t >> 4;                 // rows r = rg + 16*i, i<4
  const int cg = t & 15;                 // cols c = cg + 16*j, j<8
  const int swi = (rg & 7) * 8;
  const int sww = (cg & 7) * 8;
  float acc[4][8];
  #pragma unroll
  for (int i=0;i<4;i++)
    #pragma unroll
    for (int j=0;j<8;j++) acc[i][j] = 0.f;
  #pragma unroll
  for (int dc = 0; dc < 16; ++dc) {
    const int d = dc*4;
    const int di = d ^ swi, dw = d ^ sww;
    float4 a[4], w4[8];
    #pragma unroll
    for (int i=0;i<4;i++) a[i]  = *(const float4*)(in_t + (rg+16*i)*64 + di);
    #pragma unroll
    for (int j=0;j<8;j++) w4[j] = *(const float4*)(w_l  + (cg+16*j)*64 + dw);
    #pragma unroll
    for (int i=0;i<4;i++)
      #pragma unroll
      for (int j=0;j<8;j++)
        acc[i][j] += a[i].x*w4[j].x + a[i].y*w4[j].y + a[i].z*w4[j].z + a[i].w*w4[j].w;
  }
  double ds = 0.0, dss = 0.0;
  #pragma unroll
  for (int i=0;i<4;i++) {
    const size_t r = (size_t)r0 + rg + 16*i;
    #pragma unroll
    for (int j=0;j<8;j++) {
      const int c = cg + 16*j;
      float v = acc[i][j] + bias[c];
      outp[r*C + c] = v;
      ds += (double)v; dss += (double)v*(double)v;
    }
  }
  #pragma unroll
  for (int off = 32; off > 0; off >>= 1) {
    ds  += __shfl_down(ds, off);
    dss += __shfl_down(dss, off);
  }
  if ((t & 63) == 0) { dred[(t>>6)*2] = ds; dred[(t>>6)*2+1] = dss; }
  __syncthreads();
  if (t == 0) {
    atomicAdd(stats+0, dred[0]+dred[2]+dred[4]+dred[6]);
    atomicAdd(stats+1, dred[1]+dred[3]+dred[5]+dred[7]);
  }
}

// ---------------------------------------------------------------------------
// K3: y_p[row][k] = relu(q[k]*relu( ((ty-my)*ry) . V[:,k] )); 32 rows/block.
// ---------------------------------------------------------------------------
__global__ __launch_bounds__(256)
void k_yp(const float* __restrict__ ty, const float* __restrict__ V,
          const float* __restrict__ q, const double* __restrict__ ST,
          float* __restrict__ yp) {
  __shared__ float ty_l[32*132];
  __shared__ float vt_l[32*132];
  __shared__ float q_l[32];
  const int t = threadIdx.x;
  const int r0 = blockIdx.x * 32;
  double cy = (double)YROWS * (double)C;
  double myd = ST[2]/cy, vy = ST[3]/cy - myd*myd;
  const float my = (float)myd;
  const float ry = (float)(1.0/sqrt(vy + (double)EPS));
  #pragma unroll
  for (int s=0;s<4;s++) {
    int f = (t + 256*s)*4;
    int r = f >> 7, d = f & 127;
    float4 v = *(const float4*)(ty + (size_t)(r0+r)*C + d);
    v.x = (v.x-my)*ry; v.y = (v.y-my)*ry; v.z = (v.z-my)*ry; v.w = (v.w-my)*ry;
    *(float4*)(ty_l + r*132 + d) = v;
  }
  #pragma unroll
  for (int s=0;s<4;s++) {                 // V[d][k] -> vt[k][d]
    int f = (t + 256*s)*4;
    int d = f >> 5, k = f & 31;
    float4 v = *(const float4*)(V + f);
    vt_l[(k+0)*132 + d] = v.x;
    vt_l[(k+1)*132 + d] = v.y;
    vt_l[(k+2)*132 + d] = v.z;
    vt_l[(k+3)*132 + d] = v.w;
  }
  if (t < 32) q_l[t] = q[t];
  __syncthreads();
  const int rg = t >> 3;                  // one row
  const int kg = t & 7;                   // k = kg + 8*j
  float acc[4] = {0.f,0.f,0.f,0.f};
  #pragma unroll
  for (int dc=0; dc<32; ++dc) {
    const int d = dc*4;
    float4 a = *(const float4*)(ty_l + rg*132 + d);
    #pragma unroll
    for (int j=0;j<4;j++) {
      float4 w = *(const float4*)(vt_l + (kg+8*j)*132 + d);
      acc[j] += a.x*w.x + a.y*w.y + a.z*w.z + a.w*w.w;
    }
  }
  #pragma unroll
  for (int j=0;j<4;j++) {
    const int k = kg + 8*j;
    float v = fmaxf(acc[j], 0.f);
    v = fmaxf(q_l[k]*v, 0.f);
    yp[(size_t)(r0+rg)*KK + k] = v;
  }
}

// ---------------------------------------------------------------------------
// K4 (layer 0 only, R6 version): x_p = relu(xn@U), I = x_p@yp^T -> I fp32 +
// per-block (m, sumexp) 32-wide. 128 rows/block, grid 1024.
// ---------------------------------------------------------------------------
__global__ __launch_bounds__(256,4)
void k_xpI0(const float* __restrict__ X, const float* __restrict__ U,
            const float* __restrict__ yp, const double* __restrict__ ST,
            float* __restrict__ Ibf, float* __restrict__ Pm,
            float* __restrict__ Ps) {
  __shared__ float BUF[6784];             // xst(128x20)|ut(32x132) -> x_p(128x36) -> itile(64x44)
  __shared__ float yp_l[40*36];
  __shared__ float redm[40];
  __shared__ float sred[160];
  float* xst = BUF;
  float* ut  = BUF + 2560;
  const int t = threadIdx.x;
  const int bid = blockIdx.x;
  const int b   = bid >> 5;
  const int blk = bid & 31;
  const size_t rowbase = (size_t)b*NPG + (size_t)blk*128;
  double cx = (double)NTOT * (double)C;
  double mx = ST[0]/cx, vx = ST[1]/cx - mx*mx;
  const float rx = (float)(1.0/sqrt(vx + (double)EPS));
  const float sc = rx, sh = -(float)mx*rx;
  #pragma unroll
  for (int s=0;s<4;s++) {                 // U[d][k] -> ut[k][d]
    int f = (t + 256*s)*4;
    int d = f >> 5, k = f & 31;
    float4 v = *(const float4*)(U + f);
    ut[(k+0)*132 + d] = v.x;
    ut[(k+1)*132 + d] = v.y;
    ut[(k+2)*132 + d] = v.z;
    ut[(k+3)*132 + d] = v.w;
  }
  for (int f4 = t; f4 < 320; f4 += 256) {
    int f = f4*4;
    *(float4*)(yp_l + (f>>5)*36 + (f&31)) = *(const float4*)(yp + (size_t)b*(JJ*KK) + f);
  }
  if (t < 40) redm[t] = 0.f;

  const int rg = t >> 3;
  const int kg = t & 7;
  float acc[4][4];
  #pragma unroll
  for (int i=0;i<4;i++)
    #pragma unroll
    for (int j=0;j<4;j++) acc[i][j] = 0.f;

  for (int cc = 0; cc < 8; ++cc) {
    const int d0 = cc*16;
    __syncthreads();
    #pragma unroll
    for (int s=0;s<2;s++) {
      int idx = t + 256*s;
      int row = idx >> 2, q4 = idx & 3;
      float4 v = *(const float4*)(X + (rowbase+row)*C + d0 + 4*q4);
      v.x = v.x*sc + sh; v.y = v.y*sc + sh;
      v.z = v.z*sc + sh; v.w = v.w*sc + sh;
      *(float4*)(xst + row*20 + 4*q4) = v;
    }
    __syncthreads();
    #pragma unroll
    for (int dd4 = 0; dd4 < 4; ++dd4) {
      const int dd = dd4*4;
      float4 a[4];
      #pragma unroll
      for (int i=0;i<4;i++) a[i] = *(const float4*)(xst + (rg+32*i)*20 + dd);
      #pragma unroll
      for (int j=0;j<4;j++) {
        float4 w4 = *(const float4*)(ut + (kg+8*j)*132 + d0 + dd);
        #pragma unroll
        for (int i=0;i<4;i++)
          acc[i][j] += a[i].x*w4.x + a[i].y*w4.y + a[i].z*w4.z + a[i].w*w4.w;
      }
    }
  }
  __syncthreads();
  #pragma unroll
  for (int i=0;i<4;i++)
    #pragma unroll
    for (int j=0;j<4;j++)
      BUF[(rg+32*i)*36 + kg + 8*j] = fmaxf(acc[i][j], 0.f);
  __syncthreads();
  const int rg2 = t >> 2;
  const int jg  = t & 3;
  float ia[2][10];
  #pragma unroll
  for (int i=0;i<2;i++)
    #pragma unroll
    for (int s=0;s<10;s++) ia[i][s] = 0.f;
  #pragma unroll
  for (int half=0; half<2; ++half) {
    #pragma unroll
    for (int kc=0;kc<8;kc++) {
      const int kk4 = kc*4;
      float4 yv[5];
      #pragma unroll
      for (int s=0;s<5;s++) yv[s] = *(const float4*)(yp_l + (jg+4*(half*5+s))*36 + kk4);
      #pragma unroll
      for (int i=0;i<2;i++) {
        float4 xv = *(const float4*)(BUF + (rg2+64*i)*36 + kk4);
        #pragma unroll
        for (int s=0;s<5;s++)
          ia[i][half*5+s] += xv.x*yv[s].x + xv.y*yv[s].y + xv.z*yv[s].z + xv.w*yv[s].w;
      }
    }
  }
  #pragma unroll
  for (int s=0;s<10;s++)
    atomicMax((int*)&redm[jg+4*s], __float_as_int(fmaxf(ia[0][s], ia[1][s])));
  __syncthreads();
  float es[10];
  #pragma unroll
  for (int s=0;s<10;s++) {
    float M = redm[jg + 4*s];
    es[s] = __expf(ia[0][s] - M) + __expf(ia[1][s] - M);
  }
  #pragma unroll
  for (int s=0;s<10;s++) {
    es[s] += __shfl_xor(es[s], 4);  es[s] += __shfl_xor(es[s], 8);
    es[s] += __shfl_xor(es[s], 16); es[s] += __shfl_xor(es[s], 32);
  }
  {
    const int lane = t & 63, wv = t >> 6;
    if (lane < 4) {
      #pragma unroll
      for (int s=0;s<10;s++) sred[wv*40 + lane + 4*s] = es[s];
    }
  }
  __syncthreads();
  if (t < 40) {
    size_t po = ((size_t)b*40 + t)*32 + blk;
    Pm[po] = redm[t];
    Ps[po] = sred[t]+sred[40+t]+sred[80+t]+sred[120+t];
  }
  float* itile = BUF;
  #pragma unroll
  for (int i=0;i<2;i++) {
    __syncthreads();
    #pragma unroll
    for (int s=0;s<10;s++) itile[rg2*44 + jg + 4*s] = ia[i][s];
    __syncthreads();
    #pragma unroll
    for (int u=0;u<10;u++) {
      int f = t + 256*u;
      int r = f / 40, j = f - r*40;
      Ibf[(rowbase + 64*i + r)*JJ + j] = itile[r*44 + j];
    }
  }
}

// ---------------------------------------------------------------------------
// K_FUSED: update_l + xpI_{l+1}. 64 rows/block, grid 2048, 3 blocks/CU.
// Phases: comb(M,S) -> e -> h -> h2/gate/blend (x1 in regs) -> x1 to LDS xfull
// -> [FINAL? out] else x1 coalesced writeback + GEMM from LDS + I + partials.
// FINAL=1: out = sigmoid(sum_j I^2), nothing else written.
// ---------------------------------------------------------------------------
template<int FINAL, int NBLKIN>
__global__ __launch_bounds__(256,3)
void k_fused(float* __restrict__ x, float* __restrict__ Ibf,
             const float* __restrict__ yp, const float* __restrict__ V,
             const float* __restrict__ gw, const float* __restrict__ gb,
             const float* __restrict__ U,
             const float* __restrict__ PmIn, const float* __restrict__ PsIn,
             float* __restrict__ PmOut, float* __restrict__ PsOut,
             const double* __restrict__ ST, float* __restrict__ outp,
             const int normFlag) {
  // BUF: phaseA-C: e[0..2560) s40 | h[2560..4864) s36 | V[4864..9472) s36
  //      GEMM:     xfull[0..8448) s132 | utc[8448..9600) s36
  __shared__ float BUF[9600];
  __shared__ float ypt[32*40];
  __shared__ float M_l[40], Si_l[40];
  __shared__ float gx_l[128], gh_l[128];
  __shared__ float sredm[160], sreds[160], redm[40];
  const int t = threadIdx.x;
  const int bid = blockIdx.x;
  const int b   = bid >> 6;               // 64 blocks per graph
  const int blk = bid & 63;
  const size_t rowbase = (size_t)b*NPG + (size_t)blk*64;
  float sc = 1.f, sh = 0.f;
  if (normFlag) {
    double cx = (double)NTOT * (double)C;
    double mx = ST[0]/cx, vx = ST[1]/cx - mx*mx;
    float mxf = (float)mx, rx = (float)(1.0/sqrt(vx + (double)EPS));
    sc = rx; sh = -mxf*rx;
  }
  if (t < 40) {                           // inline comb over NBLKIN partials
    const float* pm = PmIn + ((size_t)b*40 + t)*NBLKIN;
    const float* ps = PsIn + ((size_t)b*40 + t)*NBLKIN;
    float M = 0.f;
    for (int k=0;k<NBLKIN;k++) M = fmaxf(M, pm[k]);
    float S = 0.f;
    for (int k=0;k<NBLKIN;k++) S += ps[k]*__expf(pm[k]-M);
    M_l[t] = M; Si_l[t] = 1.f/S;
  }
  if (t < 128) gx_l[t] = gw[t];
  else gh_l[t-128] = gw[t];
  for (int f4 = t; f4 < 320; f4 += 256) { // yp[b] -> ypt[k][j]
    int f = f4*4;
    int j = f >> 5;
    float4 v = *(const float4*)(yp + (size_t)b*(JJ*KK) + f);
    int k = f & 31;
    ypt[(k+0)*40 + j] = v.x;
    ypt[(k+1)*40 + j] = v.y;
    ypt[(k+2)*40 + j] = v.z;
    ypt[(k+3)*40 + j] = v.w;
  }
  #pragma unroll
  for (int s=0;s<4;s++) {                 // stage V -> BUF+4864 (s36)
    int f = (t + 256*s)*4;
    *(float4*)(BUF + 4864 + (f>>5)*36 + (f&31)) = *(const float4*)(V + f);
  }
  __syncthreads();
  for (int f4 = t; f4 < 640; f4 += 256) { // e staging (64x40 s40)
    int f = f4*4;
    int n = f / 40, j = f - n*40;
    float4 v = *(const float4*)(Ibf + (rowbase + n)*JJ + j);
    float4 e;
    e.x = __expf(v.x - M_l[j+0]) * Si_l[j+0];
    e.y = __expf(v.y - M_l[j+1]) * Si_l[j+1];
    e.z = __expf(v.z - M_l[j+2]) * Si_l[j+2];
    e.w = __expf(v.w - M_l[j+3]) * Si_l[j+3];
    *(float4*)(BUF + n*40 + j) = e;
  }
  __syncthreads();
  { // phase B: h[n][k] = relu(sum_j e*yp) -> BUF+2560 (s36)
    const int rg = t >> 3;
    const int kg = t & 7;
    float hacc[2][4];
    #pragma unroll
    for (int i=0;i<2;i++)
      #pragma unroll
      for (int j2=0;j2<4;j2++) hacc[i][j2] = 0.f;
    #pragma unroll
    for (int jc=0;jc<10;jc++) {
      const int jj = jc*4;
      float4 yv[4];
      #pragma unroll
      for (int j2=0;j2<4;j2++) yv[j2] = *(const float4*)(ypt + (kg+8*j2)*40 + jj);
      #pragma unroll
      for (int i=0;i<2;i++) {
        float4 ev = *(const float4*)(BUF + (rg+32*i)*40 + jj);
        #pragma unroll
        for (int j2=0;j2<4;j2++)
          hacc[i][j2] += ev.x*yv[j2].x + ev.y*yv[j2].y + ev.z*yv[j2].z + ev.w*yv[j2].w;
      }
    }
    #pragma unroll
    for (int i=0;i<2;i++)
      #pragma unroll
      for (int j2=0;j2<4;j2++)
        BUF[2560 + (rg+32*i)*36 + kg + 8*j2] = fmaxf(hacc[i][j2], 0.f);
  }
  __syncthreads();
  // phase C: h2 = h@V^T, gate, blend -> x1 in regs
  const int rg3 = t >> 4;                 // rows rg3*4 + i, i<4
  const int cg  = t & 15;                 // cols cg + 16*j3, j3<8
  float h2[4][8];
  #pragma unroll
  for (int i=0;i<4;i++)
    #pragma unroll
    for (int j3=0;j3<8;j3++) h2[i][j3] = 0.f;
  #pragma unroll
  for (int kc=0;kc<8;kc++) {
    const int kk2 = kc*4;
    float4 vv[8];
    #pragma unroll
    for (int j3=0;j3<8;j3++) vv[j3] = *(const float4*)(BUF + 4864 + (cg+16*j3)*36 + kk2);
    #pragma unroll
    for (int i=0;i<4;i++) {
      float4 hv = *(const float4*)(BUF + 2560 + (rg3*4+i)*36 + kk2);
      #pragma unroll
      for (int j3=0;j3<8;j3++)
        h2[i][j3] += hv.x*vv[j3].x + hv.y*vv[j3].y + hv.z*vv[j3].z + hv.w*vv[j3].w;
    }
  }
  float xn[4][8];
  float gpv[4];
  #pragma unroll
  for (int i=0;i<4;i++) {
    float g = 0.f;
    const size_t rr = (rowbase + rg3*4 + i)*C;
    #pragma unroll
    for (int j3=0;j3<8;j3++) {
      const int c = cg + 16*j3;
      float xv = x[rr + c]*sc + sh;
      xn[i][j3] = xv;
      g += gx_l[c]*xv + gh_l[c]*h2[i][j3];
    }
    gpv[i] = g;
  }
  #pragma unroll
  for (int i=0;i<4;i++) {
    gpv[i] += __shfl_xor(gpv[i], 1);
    gpv[i] += __shfl_xor(gpv[i], 2);
    gpv[i] += __shfl_xor(gpv[i], 4);
    gpv[i] += __shfl_xor(gpv[i], 8);
  }
  const float gbv = gb[0];
  #pragma unroll
  for (int i=0;i<4;i++) {
    const float z = 1.f/(1.f + __expf(-(gpv[i] + gbv)));
    #pragma unroll
    for (int j3=0;j3<8;j3++)
      xn[i][j3] = (1.f - z)*xn[i][j3] + z*h2[i][j3];   // x1
  }
  __syncthreads();                        // BUF phase A-C readers done
  #pragma unroll
  for (int i=0;i<4;i++)                   // x1 -> xfull (s132)
    #pragma unroll
    for (int j3=0;j3<8;j3++)
      BUF[(rg3*4+i)*132 + cg + 16*j3] = xn[i][j3];
  __syncthreads();
  if (!FINAL) {                           // coalesced x1 writeback from LDS
    #pragma unroll
    for (int s=0;s<8;s++) {
      int idx = t + 256*s;
      int row = idx >> 5, q4 = (idx & 31)*4;
      *(float4*)(x + (rowbase+row)*C + q4) = *(const float4*)(BUF + row*132 + q4);
    }
  }
  // GEMM: x1@U from LDS; U chunk-staged (L2-hot)
  const int r2 = t >> 2;                  // one row
  const int kq = t & 3;                   // k = kq + 4*i, i<8
  float acc[8];
  #pragma unroll
  for (int i=0;i<8;i++) acc[i] = 0.f;
  for (int cc=0; cc<4; ++cc) {
    const int d0 = cc*32;
    for (int f = t; f < 1152; f += 256) { // utc[k][dl] s36 at BUF+8448
      int dl = f >> 5, k = f & 31;
      BUF[8448 + k*36 + dl] = U[(size_t)(d0+dl)*KK + k];
    }
    __syncthreads();
    #pragma unroll
    for (int dd4=0; dd4<8; ++dd4) {
      const int dd = dd4*4;
      float4 a0 = *(const float4*)(BUF + r2*132 + d0 + dd);
      #pragma unroll
      for (int i=0;i<8;i++) {
        float4 w = *(const float4*)(BUF + 8448 + (kq+4*i)*36 + dd);
        acc[i] += a0.x*w.x + a0.y*w.y + a0.z*w.z + a0.w*w.w;
      }
    }
    __syncthreads();
  }
  float xp[8];
  #pragma unroll
  for (int i=0;i<8;i++) xp[i] = fmaxf(acc[i], 0.f);
  // I-phase: p = x_p @ yp^T, full row after cross-kq reduce
  float4 p[10];
  #pragma unroll
  for (int m=0;m<10;m++) { p[m].x=0.f; p[m].y=0.f; p[m].z=0.f; p[m].w=0.f; }
  #pragma unroll
  for (int i=0;i<8;i++) {
    const float xv = xp[i];
    const float* yb = ypt + (kq+4*i)*40;
    #pragma unroll
    for (int m=0;m<10;m++) {
      float4 yv = *(const float4*)(yb + 4*m);
      p[m].x += xv*yv.x; p[m].y += xv*yv.y;
      p[m].z += xv*yv.z; p[m].w += xv*yv.w;
    }
  }
  #pragma unroll
  for (int m=0;m<10;m++) {
    p[m].x += __shfl_xor(p[m].x,1); p[m].x += __shfl_xor(p[m].x,2);
    p[m].y += __shfl_xor(p[m].y,1); p[m].y += __shfl_xor(p[m].y,2);
    p[m].z += __shfl_xor(p[m].z,1); p[m].z += __shfl_xor(p[m].z,2);
    p[m].w += __shfl_xor(p[m].w,1); p[m].w += __shfl_xor(p[m].w,2);
  }
  if (FINAL) {
    float s = 0.f;
    #pragma unroll
    for (int m=0;m<10;m++)
      s += p[m].x*p[m].x + p[m].y*p[m].y + p[m].z*p[m].z + p[m].w*p[m].w;
    if (kq == 0) outp[rowbase + r2] = 1.f/(1.f+__expf(-s));
    return;
  }
  if (kq == 0) {                          // I write: 160 B contiguous per active lane
    float* dst = Ibf + (rowbase + r2)*JJ;
    #pragma unroll
    for (int m=0;m<10;m++) *(float4*)(dst + 4*m) = p[m];
  }
  float ev[10];
  #pragma unroll
  for (int m=0;m<10;m++) {                // j = 4m+kq component
    float4 qv = p[m];
    ev[m] = (kq&1) ? ((kq&2)? qv.w : qv.y) : ((kq&2)? qv.z : qv.x);
  }
  const int w = t >> 6, tl = t & 63;
  float mv[10];
  #pragma unroll
  for (int m=0;m<10;m++) {
    mv[m] = ev[m];
    mv[m] = fmaxf(mv[m], __shfl_xor(mv[m], 4));
    mv[m] = fmaxf(mv[m], __shfl_xor(mv[m], 8));
    mv[m] = fmaxf(mv[m], __shfl_xor(mv[m], 16));
    mv[m] = fmaxf(mv[m], __shfl_xor(mv[m], 32));
  }
  if (tl < 4) {
    #pragma unroll
    for (int m=0;m<10;m++) sredm[w*40 + 4*m + kq] = mv[m];
  }
  __syncthreads();
  if (t < 40)
    redm[t] = fmaxf(fmaxf(sredm[t], sredm[40+t]), fmaxf(sredm[80+t], sredm[120+t]));
  __syncthreads();
  float es[10];
  #pragma unroll
  for (int m=0;m<10;m++) {
    float M = redm[4*m + kq];
    es[m] = __expf(ev[m]-M);
    es[m] += __shfl_xor(es[m], 4);
    es[m] += __shfl_xor(es[m], 8);
    es[m] += __shfl_xor(es[m], 16);
    es[m] += __shfl_xor(es[m], 32);
  }
  if (tl < 4) {
    #pragma unroll
    for (int m=0;m<10;m++) sreds[w*40 + 4*m + kq] = es[m];
  }
  __syncthreads();
  if (t < 40) {
    size_t po = ((size_t)b*40 + t)*64 + blk;
    PmOut[po] = redm[t];
    PsOut[po] = sreds[t]+sreds[40+t]+sreds[80+t]+sreds[120+t];
  }
}

extern "C" void kernel_launch(void* const* d_in, const int* in_sizes, int n_in,
                              void* d_out, int out_size, void* d_ws, size_t ws_size,
                              hipStream_t stream) {
  const float* nf  = (const float*)d_in[0];
  const float* fe  = (const float*)d_in[1];
  const float* W   = (const float*)d_in[2];
  const float* bin = (const float*)d_in[3];
  const float* U   = (const float*)d_in[4];
  const float* V   = (const float*)d_in[5];
  const float* q   = (const float*)d_in[6];
  const float* gw  = (const float*)d_in[7];
  const float* gb  = (const float*)d_in[8];
  float* out = (float*)d_out;
  float* wf  = (float*)d_ws;

  float*  X   = wf + X_OFF;
  float*  Ibf = wf + I_OFF;
  float*  TY  = wf + TY_OFF;
  float*  YP  = wf + YP_OFF;
  float*  PM  = wf + PM_OFF;
  float*  PS  = wf + PS_OFF;
  float*  PM2 = wf + PM2_OFF;
  float*  PS2 = wf + PS2_OFF;
  double* ST  = (double*)(wf + ST_OFF);

  hipMemsetAsync(ST, 0, 4*sizeof(double), stream);

  k_gemm_in<<<NTOT/64, 256, 0, stream>>>(nf, W, bin, X, ST);
  k_gemm_in<<<YROWS/64, 256, 0, stream>>>(fe, W, bin, TY, ST+2);
  k_yp<<<YROWS/32, 256, 0, stream>>>(TY, V, q, ST, YP);

  // layer 0: x_p / I / softmax partials (32-wide)
  k_xpI0<<<1024, 256, 0, stream>>>(X, U, YP, ST, Ibf, PM, PS);
  // fused: update_0 + xpI_1 (reads 32-wide partials, writes 64-wide)
  k_fused<0,32><<<2048, 256, 0, stream>>>(X, Ibf, YP, V, gw, gb, U,
                                          PM, PS, PM2, PS2, ST, nullptr, 1);
  // fused: update_1 + final (out = sigmoid(sum_j I^2))
  k_fused<1,64><<<2048, 256, 0, stream>>>(X, Ibf, YP, V, gw, gb, U,
                                          PM2, PS2, nullptr, nullptr, ST, out, 0);
}